// Round 1
// baseline (253.936 us; speedup 1.0000x reference)
//
#include <hip/hip_runtime.h>
#include <math.h>

// ---- constants -------------------------------------------------------------
#define BATCH   32
#define LSEQ    1000
#define LPAD    1024
#define EMBD    512      // embedding dim == K of projections
#define DMODEL  512
#define NHEADS  8
#define DHEAD   64
#define NKV     1024     // K cols (512) ++ V cols (512)

typedef __attribute__((ext_vector_type(8))) short s8v;   // 8 x bf16 (4 VGPRs)
typedef __attribute__((ext_vector_type(4))) float f4v;   // MFMA accumulator

__device__ __forceinline__ unsigned short f2bf(float f) {
  unsigned u = __builtin_bit_cast(unsigned, f);
  u += 0x7fffu + ((u >> 16) & 1u);           // RNE
  return (unsigned short)(u >> 16);
}
__device__ __forceinline__ float bf2f(unsigned short h) {
  return __builtin_bit_cast(float, ((unsigned)h) << 16);
}
__device__ __forceinline__ void g2lds16(const void* g, void* l) {
  __builtin_amdgcn_global_load_lds((const __attribute__((address_space(1))) void*)g,
                                   (__attribute__((address_space(3))) void*)l,
                                   16, 0, 0);
}

// ---- kernel 1: weights -> bf16 B^T layout (Wk ++ Wv), bias concat ----------
__global__ __launch_bounds__(256) void prep_kernel(
    const float* __restrict__ Wk, const float* __restrict__ bk,
    const float* __restrict__ Wv, const float* __restrict__ bv,
    unsigned short* __restrict__ Bkv, float* __restrict__ bias_kv) {
  int idx = blockIdx.x * 256 + threadIdx.x;      // 131072 threads, 4 floats each
  int off = idx * 4;                             // flat element offset, 0..524287
  const float* s = (off < 262144) ? (Wk + off) : (Wv + off - 262144);
  float4 v = *(const float4*)s;
  unsigned r0 = (unsigned)f2bf(v.x) | ((unsigned)f2bf(v.y) << 16);
  unsigned r1 = (unsigned)f2bf(v.z) | ((unsigned)f2bf(v.w) << 16);
  uint2 pk; pk.x = r0; pk.y = r1;
  *(uint2*)(Bkv + off) = pk;
  if (idx < 1024) bias_kv[idx] = (idx < 512) ? bk[idx] : bv[idx - 512];
}

// ---- kernel 2: X[b][j][e] = bf16( emb[data[b,j]][e] + pe[j][e] ), j<=p_b ---
__global__ __launch_bounds__(256) void build_x_kernel(
    const int* __restrict__ data, const int* __restrict__ lengths,
    const float* __restrict__ emb, unsigned short* __restrict__ X) {
  int t    = threadIdx.x;
  int row  = blockIdx.x * 4 + (t >> 6);          // 0..31999
  int b    = row / 1000;
  int j    = row - b * 1000;
  int p    = lengths[b] - 1;
  if (j > p) return;                             // rows beyond last pos unused
  int lane = t & 63;
  int e0   = lane * 8;
  int tok  = data[row];
  const float* ev = emb + (size_t)tok * 512 + e0;
  float4 a = *(const float4*)(ev);
  float4 c = *(const float4*)(ev + 4);
  float vals[8] = {a.x, a.y, a.z, a.w, c.x, c.y, c.z, c.w};
  #pragma unroll
  for (int i = 0; i < 8; i += 2) {
    int e = e0 + i;                              // even
    float dv  = expf((float)e * (-9.210340371976184f / 512.0f)); // 10000^{-e/512}
    float arg = (float)j * dv;
    float sn, cs;
    sincosf(arg, &sn, &cs);
    vals[i]     += sn;
    vals[i + 1] += cs;
  }
  unsigned w0 = (unsigned)f2bf(vals[0]) | ((unsigned)f2bf(vals[1]) << 16);
  unsigned w1 = (unsigned)f2bf(vals[2]) | ((unsigned)f2bf(vals[3]) << 16);
  unsigned w2 = (unsigned)f2bf(vals[4]) | ((unsigned)f2bf(vals[5]) << 16);
  unsigned w3 = (unsigned)f2bf(vals[6]) | ((unsigned)f2bf(vals[7]) << 16);
  uint4 pk; pk.x = w0; pk.y = w1; pk.z = w2; pk.w = w3;
  *(uint4*)(X + ((size_t)(b * LPAD + j)) * 512 + e0) = pk;
}

// ---- kernel 3: KV GEMM, C[b][j][0:512]=K, [512:1024]=V  (bf16 MFMA) --------
// 128x128 tile, BK=64, 4 waves of 64x64 (4x4 MFMA 16x16x32), XOR-swizzled LDS.
__global__ __launch_bounds__(256) void kv_gemm_kernel(
    const unsigned short* __restrict__ X, const unsigned short* __restrict__ Bkv,
    const float* __restrict__ bias_kv, const int* __restrict__ lengths,
    unsigned short* __restrict__ C) {
  int b    = blockIdx.z;
  int row0 = blockIdx.y * 128;
  int p    = lengths[b] - 1;
  if (row0 > p) return;                          // skip tiles past last position
  int n0   = blockIdx.x * 128;

  __shared__ unsigned short lA[128 * 64];        // 16 KB
  __shared__ unsigned short lB[128 * 64];        // 16 KB

  int t = threadIdx.x;
  int w = t >> 6;                                // wave 0..3
  int lane = t & 63;
  int wm = w & 1, wn = w >> 1;                   // wave tile: m=wm*64, n=wn*64

  f4v acc[4][4];
  f4v z = {0.0f, 0.0f, 0.0f, 0.0f};
  #pragma unroll
  for (int i = 0; i < 4; ++i)
    #pragma unroll
    for (int jn = 0; jn < 4; ++jn) acc[i][jn] = z;

  // staging source pointers (chunk-of-16B assignments with XOR swizzle)
  const unsigned short* gA[4];
  const unsigned short* gB[4];
  #pragma unroll
  for (int i = 0; i < 4; ++i) {
    int chunk = (i * 4 + w) * 64 + lane;         // 0..1023
    int r  = chunk >> 3;                         // row within tile
    int cc = (chunk & 7) ^ (r & 7);              // swizzled 16B-chunk column
    gA[i] = X   + ((size_t)(b * LPAD + row0 + r)) * 512 + cc * 8;
    gB[i] = Bkv + ((size_t)(n0 + r)) * 512 + cc * 8;
  }

  int q  = lane >> 4;                            // quad 0..3
  int ml = lane & 15;

  for (int kt = 0; kt < 8; ++kt) {               // K = 512, BK = 64
    #pragma unroll
    for (int i = 0; i < 4; ++i) {
      g2lds16(gA[i] + kt * 64, lA + (i * 4 + w) * 512);
      g2lds16(gB[i] + kt * 64, lB + (i * 4 + w) * 512);
    }
    __syncthreads();
    #pragma unroll
    for (int kk = 0; kk < 2; ++kk) {             // two k-steps of 32
      s8v af[4], bf[4];
      #pragma unroll
      for (int mb = 0; mb < 4; ++mb) {
        int m  = wm * 64 + mb * 16 + ml;
        int ch = m * 8 + ((kk * 4 + q) ^ (m & 7));
        af[mb] = *(const s8v*)(&lA[ch * 8]);
      }
      #pragma unroll
      for (int nb = 0; nb < 4; ++nb) {
        int n  = wn * 64 + nb * 16 + ml;
        int ch = n * 8 + ((kk * 4 + q) ^ (n & 7));
        bf[nb] = *(const s8v*)(&lB[ch * 8]);
      }
      #pragma unroll
      for (int mb = 0; mb < 4; ++mb)
        #pragma unroll
        for (int nb = 0; nb < 4; ++nb)
          acc[mb][nb] = __builtin_amdgcn_mfma_f32_16x16x32_bf16(
              af[mb], bf[nb], acc[mb][nb], 0, 0, 0);
    }
    __syncthreads();
  }

  // epilogue: D row = q*4+reg, col = lane&15  (m89-verified layout) + bias
  #pragma unroll
  for (int mb = 0; mb < 4; ++mb) {
    int row = row0 + wm * 64 + mb * 16 + q * 4;
    #pragma unroll
    for (int nb = 0; nb < 4; ++nb) {
      int col = n0 + wn * 64 + nb * 16 + ml;
      float bias = bias_kv[col];
      size_t base = ((size_t)(b * LPAD + row)) * NKV + col;
      #pragma unroll
      for (int r2 = 0; r2 < 4; ++r2)
        C[base + (size_t)r2 * NKV] = f2bf(acc[mb][nb][r2] + bias);
    }
  }
}

// ---- kernel 4: q[b] = x[b, p_b] @ Wq^T + bq  (one row per batch) -----------
__global__ __launch_bounds__(256) void q_proj_kernel(
    const unsigned short* __restrict__ X, const int* __restrict__ lengths,
    const float* __restrict__ Wq, const float* __restrict__ bq,
    float* __restrict__ qout) {
  int b = blockIdx.x;
  int p = lengths[b] - 1;
  int t = threadIdx.x;
  __shared__ float xs[512];
  const unsigned short* xr = X + ((size_t)(b * LPAD + p)) * 512;
  xs[t]       = bf2f(xr[t]);
  xs[t + 256] = bf2f(xr[t + 256]);
  __syncthreads();
  #pragma unroll
  for (int nn = 0; nn < 2; ++nn) {
    int n = t + nn * 256;
    const float* wr = Wq + (size_t)n * 512;
    float a = bq[n];
    for (int e = 0; e < 512; e += 4) {
      float4 wv = *(const float4*)(wr + e);
      a += wv.x * xs[e] + wv.y * xs[e + 1] + wv.z * xs[e + 2] + wv.w * xs[e + 3];
    }
    qout[b * 512 + n] = a;
  }
}

// ---- kernel 5: single-row causal attention per (b, h) ----------------------
__global__ __launch_bounds__(256) void attn_kernel(
    const float* __restrict__ qv, const unsigned short* __restrict__ C,
    const int* __restrict__ lengths, float* __restrict__ ctx) {
  int h = blockIdx.x, b = blockIdx.y;
  int n_keys = lengths[b];                       // p_b + 1, in [1,1000]
  int t = threadIdx.x;
  __shared__ float qs[64];
  __shared__ float probs[LSEQ];
  __shared__ float wred[4];
  __shared__ float cred[256];
  if (t < 64) qs[t] = qv[b * 512 + h * 64 + t] * 0.125f;   // 1/sqrt(64)
  __syncthreads();

  // pass 1: scores
  float lmax = -INFINITY;
  for (int j = t; j < n_keys; j += 256) {
    const unsigned short* kr = C + ((size_t)(b * LPAD + j)) * NKV + h * 64;
    float s = 0.0f;
    #pragma unroll
    for (int e = 0; e < 64; e += 8) {
      uint4 u = *(const uint4*)(kr + e);
      unsigned uu[4] = {u.x, u.y, u.z, u.w};
      #pragma unroll
      for (int wi = 0; wi < 4; ++wi) {
        float lo = __builtin_bit_cast(float, uu[wi] << 16);
        float hi = __builtin_bit_cast(float, uu[wi] & 0xffff0000u);
        s += lo * qs[e + wi * 2] + hi * qs[e + wi * 2 + 1];
      }
    }
    probs[j] = s;
    lmax = fmaxf(lmax, s);
  }
  #pragma unroll
  for (int o = 32; o > 0; o >>= 1) lmax = fmaxf(lmax, __shfl_xor(lmax, o, 64));
  if ((t & 63) == 0) wred[t >> 6] = lmax;
  __syncthreads();
  float gmax = fmaxf(fmaxf(wred[0], wred[1]), fmaxf(wred[2], wred[3]));
  __syncthreads();

  float lsum = 0.0f;
  for (int j = t; j < n_keys; j += 256) {
    float pe = __expf(probs[j] - gmax);
    probs[j] = pe;
    lsum += pe;
  }
  #pragma unroll
  for (int o = 32; o > 0; o >>= 1) lsum += __shfl_xor(lsum, o, 64);
  if ((t & 63) == 0) wred[t >> 6] = lsum;
  __syncthreads();
  float inv = 1.0f / (wred[0] + wred[1] + wred[2] + wred[3]);

  // pass 2: ctx_d = (sum_j p_j * V[j][d]) * inv ; lane owns d, wave strides j
  int lane = t & 63, wv2 = t >> 6;
  float a0 = 0.0f;
  for (int j = wv2; j < n_keys; j += 4) {
    float pj = probs[j];                         // wave-uniform -> LDS broadcast
    float vvv = bf2f(C[((size_t)(b * LPAD + j)) * NKV + 512 + h * 64 + lane]);
    a0 += pj * vvv;
  }
  cred[t] = a0;
  __syncthreads();
  if (t < 64) {
    float r = cred[t] + cred[t + 64] + cred[t + 128] + cred[t + 192];
    ctx[b * 512 + h * 64 + t] = r * inv;
  }
}

// ---- kernel 6: MLP head: leaky(mean(relu(W2 leaky(W1 ctx + b1) + b2))) -----
__global__ __launch_bounds__(256) void final_kernel(
    const float* __restrict__ ctx, const float* __restrict__ W1,
    const float* __restrict__ b1, const float* __restrict__ W2,
    const float* __restrict__ b2, float* __restrict__ out) {
  int b = blockIdx.x, t = threadIdx.x;
  __shared__ float xs[512];
  __shared__ float hs[512];
  __shared__ float o8[8];
  xs[t]       = ctx[b * 512 + t];
  xs[t + 256] = ctx[b * 512 + t + 256];
  __syncthreads();
  #pragma unroll
  for (int nn = 0; nn < 2; ++nn) {
    int n = t + nn * 256;
    const float* wr = W1 + (size_t)n * 512;
    float a = b1[n];
    for (int e = 0; e < 512; e += 4) {
      float4 wv = *(const float4*)(wr + e);
      a += wv.x * xs[e] + wv.y * xs[e + 1] + wv.z * xs[e + 2] + wv.w * xs[e + 3];
    }
    hs[n] = (a > 0.0f) ? a : 0.01f * a;          // leaky_relu
  }
  __syncthreads();
  int j = t >> 5, sub = t & 31;
  const float* w2r = W2 + (size_t)j * 512;
  float part = 0.0f;
  for (int e = sub * 16; e < sub * 16 + 16; e += 4) {
    float4 wv = *(const float4*)(w2r + e);
    part += wv.x * hs[e] + wv.y * hs[e + 1] + wv.z * hs[e + 2] + wv.w * hs[e + 3];
  }
  #pragma unroll
  for (int o = 16; o > 0; o >>= 1) part += __shfl_xor(part, o, 64);
  if (sub == 0) o8[j] = fmaxf(part + b2[j], 0.0f);   // relu
  __syncthreads();
  if (t == 0) {
    float m = 0.0f;
    #pragma unroll
    for (int i = 0; i < 8; ++i) m += o8[i];
    m *= 0.125f;                                  // mean over 8
    out[b] = (m > 0.0f) ? m : 0.01f * m;          // leaky_relu
  }
}

// ---- launcher --------------------------------------------------------------
extern "C" void kernel_launch(void* const* d_in, const int* in_sizes, int n_in,
                              void* d_out, int out_size, void* d_ws, size_t ws_size,
                              hipStream_t stream) {
  const int*   data    = (const int*)d_in[0];
  const int*   lengths = (const int*)d_in[1];
  const float* emb     = (const float*)d_in[2];
  const float* Wq      = (const float*)d_in[3];
  const float* bq      = (const float*)d_in[4];
  const float* Wk      = (const float*)d_in[5];
  const float* bk      = (const float*)d_in[6];
  const float* Wv      = (const float*)d_in[7];
  const float* bv      = (const float*)d_in[8];
  const float* W1      = (const float*)d_in[9];
  const float* b1      = (const float*)d_in[10];
  const float* W2      = (const float*)d_in[11];
  const float* b2      = (const float*)d_in[12];
  float* out = (float*)d_out;

  char* ws = (char*)d_ws;
  unsigned short* X    = (unsigned short*)(ws);                  // 33,554,432 B
  unsigned short* C    = (unsigned short*)(ws + 33554432);       // 67,108,864 B
  unsigned short* Bkv  = (unsigned short*)(ws + 100663296);      //  1,048,576 B
  float* bias_kv       = (float*)(ws + 101711872);               //      4,096 B
  float* qv            = (float*)(ws + 101715968);               //     65,536 B
  float* ctx           = (float*)(ws + 101781504);               //     65,536 B

  prep_kernel<<<512, 256, 0, stream>>>(Wk, bk, Wv, bv, Bkv, bias_kv);
  build_x_kernel<<<8000, 256, 0, stream>>>(data, lengths, emb, X);
  dim3 g3(8, 8, BATCH);
  kv_gemm_kernel<<<g3, 256, 0, stream>>>(X, Bkv, bias_kv, lengths, C);
  q_proj_kernel<<<BATCH, 256, 0, stream>>>(X, lengths, Wq, bq, qv);
  dim3 g5(NHEADS, BATCH);
  attn_kernel<<<g5, 256, 0, stream>>>(qv, C, lengths, ctx);
  final_kernel<<<BATCH, 256, 0, stream>>>(ctx, W1, b1, W2, b2, out);
}

// Round 2
// 173.693 us; speedup vs baseline: 1.4620x; 1.4620x over previous
//
#include <hip/hip_runtime.h>
#include <math.h>

// ---- constants -------------------------------------------------------------
#define BATCH   32
#define LSEQ    1000
#define LPAD    1024
#define NHEADS  8
#define DHEAD   64

typedef __attribute__((ext_vector_type(8))) short s8v;   // 8 x bf16 (4 VGPRs)
typedef __attribute__((ext_vector_type(4))) float f4v;   // MFMA accumulator

__device__ __forceinline__ unsigned short f2bf(float f) {
  unsigned u = __builtin_bit_cast(unsigned, f);
  u += 0x7fffu + ((u >> 16) & 1u);           // RNE
  return (unsigned short)(u >> 16);
}
__device__ __forceinline__ float bf2f(unsigned short h) {
  return __builtin_bit_cast(float, ((unsigned)h) << 16);
}
__device__ __forceinline__ void g2lds16(const void* g, void* l) {
  __builtin_amdgcn_global_load_lds((const __attribute__((address_space(1))) void*)g,
                                   (__attribute__((address_space(3))) void*)l,
                                   16, 0, 0);
}

// ---- kernel 1: weights -> bf16 B^T layout (Wk ++ Wv), bias concat ----------
__global__ __launch_bounds__(256) void prep_kernel(
    const float* __restrict__ Wk, const float* __restrict__ bk,
    const float* __restrict__ Wv, const float* __restrict__ bv,
    unsigned short* __restrict__ Bkv, float* __restrict__ bias_kv) {
  int idx = blockIdx.x * 256 + threadIdx.x;      // 131072 threads, 4 floats each
  int off = idx * 4;
  const float* s = (off < 262144) ? (Wk + off) : (Wv + off - 262144);
  float4 v = *(const float4*)s;
  unsigned r0 = (unsigned)f2bf(v.x) | ((unsigned)f2bf(v.y) << 16);
  unsigned r1 = (unsigned)f2bf(v.z) | ((unsigned)f2bf(v.w) << 16);
  uint2 pk; pk.x = r0; pk.y = r1;
  *(uint2*)(Bkv + off) = pk;
  if (idx < 1024) bias_kv[idx] = (idx < 512) ? bk[idx] : bv[idx - 512];
}

// ---- kernel 2: X[b][j][e] = bf16( emb[data[b,j]][e] + pe[j][e] ), j<=p_b ---
__global__ __launch_bounds__(256) void build_x_kernel(
    const int* __restrict__ data, const int* __restrict__ lengths,
    const float* __restrict__ emb, unsigned short* __restrict__ X) {
  int t    = threadIdx.x;
  int row  = blockIdx.x * 4 + (t >> 6);          // 0..31999
  int b    = row / 1000;
  int j    = row - b * 1000;
  int p    = lengths[b] - 1;
  if (j > p) return;
  int lane = t & 63;
  int e0   = lane * 8;
  int tok  = data[row];
  const float* ev = emb + (size_t)tok * 512 + e0;
  float4 a = *(const float4*)(ev);
  float4 c = *(const float4*)(ev + 4);
  float vals[8] = {a.x, a.y, a.z, a.w, c.x, c.y, c.z, c.w};
  #pragma unroll
  for (int i = 0; i < 8; i += 2) {
    int e = e0 + i;                              // even
    float dv  = __expf((float)e * (-9.210340371976184f / 512.0f)); // 10000^{-e/512}
    float arg = (float)j * dv;
    vals[i]     += __sinf(arg);
    vals[i + 1] += __cosf(arg);
  }
  unsigned w0 = (unsigned)f2bf(vals[0]) | ((unsigned)f2bf(vals[1]) << 16);
  unsigned w1 = (unsigned)f2bf(vals[2]) | ((unsigned)f2bf(vals[3]) << 16);
  unsigned w2 = (unsigned)f2bf(vals[4]) | ((unsigned)f2bf(vals[5]) << 16);
  unsigned w3 = (unsigned)f2bf(vals[6]) | ((unsigned)f2bf(vals[7]) << 16);
  uint4 pk; pk.x = w0; pk.y = w1; pk.z = w2; pk.w = w3;
  *(uint4*)(X + ((size_t)(b * LPAD + j)) * 512 + e0) = pk;
}

// ---- kernel 3: KV GEMM -> head-major Ck[b][h][j][64], Cv[b][h][j][64] ------
// 128x128 tile, BK=64, 4 waves of 64x64 (4x4 MFMA 16x16x32), XOR-swizzled LDS.
__global__ __launch_bounds__(256) void kv_gemm_kernel(
    const unsigned short* __restrict__ X, const unsigned short* __restrict__ Bkv,
    const float* __restrict__ bias_kv, const int* __restrict__ lengths,
    unsigned short* __restrict__ Ck, unsigned short* __restrict__ Cv) {
  int b    = blockIdx.z;
  int row0 = blockIdx.y * 128;
  int p    = lengths[b] - 1;
  if (row0 > p) return;
  int n0   = blockIdx.x * 128;                   // 0..896 over K(512)++V(512)

  __shared__ unsigned short lA[128 * 64];        // 16 KB
  __shared__ unsigned short lB[128 * 64];        // 16 KB

  int t = threadIdx.x;
  int w = t >> 6;
  int lane = t & 63;
  int wm = w & 1, wn = w >> 1;

  f4v acc[4][4];
  f4v z = {0.0f, 0.0f, 0.0f, 0.0f};
  #pragma unroll
  for (int i = 0; i < 4; ++i)
    #pragma unroll
    for (int jn = 0; jn < 4; ++jn) acc[i][jn] = z;

  const unsigned short* gA[4];
  const unsigned short* gB[4];
  #pragma unroll
  for (int i = 0; i < 4; ++i) {
    int chunk = (i * 4 + w) * 64 + lane;
    int r  = chunk >> 3;
    int cc = (chunk & 7) ^ (r & 7);
    gA[i] = X   + ((size_t)(b * LPAD + row0 + r)) * 512 + cc * 8;
    gB[i] = Bkv + ((size_t)(n0 + r)) * 512 + cc * 8;
  }

  int q  = lane >> 4;
  int ml = lane & 15;

  for (int kt = 0; kt < 8; ++kt) {               // K = 512, BK = 64
    #pragma unroll
    for (int i = 0; i < 4; ++i) {
      g2lds16(gA[i] + kt * 64, lA + (i * 4 + w) * 512);
      g2lds16(gB[i] + kt * 64, lB + (i * 4 + w) * 512);
    }
    __syncthreads();
    #pragma unroll
    for (int kk = 0; kk < 2; ++kk) {
      s8v af[4], bfr[4];
      #pragma unroll
      for (int mb = 0; mb < 4; ++mb) {
        int m  = wm * 64 + mb * 16 + ml;
        int ch = m * 8 + ((kk * 4 + q) ^ (m & 7));
        af[mb] = *(const s8v*)(&lA[ch * 8]);
      }
      #pragma unroll
      for (int nb = 0; nb < 4; ++nb) {
        int n  = wn * 64 + nb * 16 + ml;
        int ch = n * 8 + ((kk * 4 + q) ^ (n & 7));
        bfr[nb] = *(const s8v*)(&lB[ch * 8]);
      }
      #pragma unroll
      for (int mb = 0; mb < 4; ++mb)
        #pragma unroll
        for (int nb = 0; nb < 4; ++nb)
          acc[mb][nb] = __builtin_amdgcn_mfma_f32_16x16x32_bf16(
              af[mb], bfr[nb], acc[mb][nb], 0, 0, 0);
    }
    __syncthreads();
  }

  // epilogue: D row = q*4+reg, col = lane&15; write head-major K or V
  bool isK = (n0 < 512);
  unsigned short* Cout = isK ? Ck : Cv;
  int nbase = isK ? n0 : (n0 - 512);
  #pragma unroll
  for (int mb = 0; mb < 4; ++mb) {
    int row = row0 + wm * 64 + mb * 16 + q * 4;
    #pragma unroll
    for (int nb = 0; nb < 4; ++nb) {
      int col = nbase + wn * 64 + nb * 16 + ml;  // 0..511 within K or V
      int hh = col >> 6, d = col & 63;
      float bias = bias_kv[isK ? col : col + 512];
      size_t baseo = ((size_t)(b * NHEADS + hh) * LPAD + row) * 64 + d;
      #pragma unroll
      for (int r2 = 0; r2 < 4; ++r2)
        Cout[baseo + (size_t)r2 * 64] = f2bf(acc[mb][nb][r2] + bias);
    }
  }
}

// ---- kernel 4: q[b] = x[b, p_b] @ Wq^T + bq  (8 col-chunks x 32 b) ---------
__global__ __launch_bounds__(256) void q_proj_kernel(
    const unsigned short* __restrict__ X, const int* __restrict__ lengths,
    const float* __restrict__ Wq, const float* __restrict__ bq,
    float* __restrict__ qout) {
  int chunk = blockIdx.x, b = blockIdx.y;
  int p = lengths[b] - 1;
  int t = threadIdx.x;
  __shared__ float xs[512];
  __shared__ float red[256];
  const unsigned short* xr = X + ((size_t)(b * LPAD + p)) * 512;
  xs[t]       = bf2f(xr[t]);
  xs[t + 256] = bf2f(xr[t + 256]);
  __syncthreads();
  int col = chunk * 64 + (t & 63);
  int kp  = t >> 6;                              // 4-way K split
  const float* wr = Wq + (size_t)col * 512 + kp * 128;
  const float* xp = xs + kp * 128;
  float a = 0.0f;
  for (int e = 0; e < 128; e += 4) {
    float4 wv = *(const float4*)(wr + e);
    a += wv.x * xp[e] + wv.y * xp[e + 1] + wv.z * xp[e + 2] + wv.w * xp[e + 3];
  }
  red[t] = a;
  __syncthreads();
  if (t < 64)
    qout[b * 512 + chunk * 64 + t] =
        red[t] + red[t + 64] + red[t + 128] + red[t + 192] + bq[chunk * 64 + t];
}

// ---- kernel 5: attention partials per (chunk of 128 keys, h, b) ------------
__global__ __launch_bounds__(128) void attn_part_kernel(
    const float* __restrict__ qv, const unsigned short* __restrict__ Ck,
    const unsigned short* __restrict__ Cv, const int* __restrict__ lengths,
    float* __restrict__ part) {
  int c = blockIdx.x, h = blockIdx.y, b = blockIdx.z;
  int n_keys = lengths[b];
  int j0 = c * 128;
  if (j0 >= n_keys) return;
  int t = threadIdx.x;
  __shared__ float qs[64];
  __shared__ float redm[2];
  __shared__ float reds[2];
  __shared__ float probs[128];
  __shared__ float ored[128];
  if (t < 64) qs[t] = qv[b * 512 + h * 64 + t] * 0.125f;   // 1/sqrt(64)
  __syncthreads();
  int bh = b * NHEADS + h;
  int j = j0 + t;
  bool valid = j < n_keys;
  const unsigned short* kr = Ck + ((size_t)bh * LPAD + j) * 64;
  float s = 0.0f;
  #pragma unroll
  for (int e = 0; e < 64; e += 8) {
    uint4 u = *(const uint4*)(kr + e);
    unsigned uu[4] = {u.x, u.y, u.z, u.w};
    #pragma unroll
    for (int wi = 0; wi < 4; ++wi) {
      float lo = __builtin_bit_cast(float, uu[wi] << 16);
      float hi = __builtin_bit_cast(float, uu[wi] & 0xffff0000u);
      s += lo * qs[e + wi * 2] + hi * qs[e + wi * 2 + 1];
    }
  }
  float sc = valid ? s : -INFINITY;
  float wm = sc;
  #pragma unroll
  for (int o = 32; o > 0; o >>= 1) wm = fmaxf(wm, __shfl_xor(wm, o, 64));
  if ((t & 63) == 0) redm[t >> 6] = wm;
  __syncthreads();
  float m = fmaxf(redm[0], redm[1]);
  float pp = valid ? __expf(s - m) : 0.0f;
  probs[t] = pp;
  float ws_ = pp;
  #pragma unroll
  for (int o = 32; o > 0; o >>= 1) ws_ += __shfl_xor(ws_, o, 64);
  if ((t & 63) == 0) reds[t >> 6] = ws_;
  __syncthreads();
  // pass 2: lane owns d, 2 waves stride j
  int lane = t & 63, w = t >> 6;
  const unsigned short* vr = Cv + ((size_t)bh * LPAD + j0) * 64 + lane;
  float a = 0.0f;
  for (int jl = w; jl < 128; jl += 2)
    a += probs[jl] * bf2f(vr[(size_t)jl * 64]);
  ored[t] = a;
  __syncthreads();
  size_t pi = ((size_t)bh * 8 + c) * 66;
  if (t < 64) part[pi + 2 + t] = ored[t] + ored[t + 64];
  if (t == 0) { part[pi] = m; part[pi + 1] = reds[0] + reds[1]; }
}

// ---- kernel 6: combine chunk partials -> ctx -------------------------------
__global__ __launch_bounds__(64) void attn_combine_kernel(
    const float* __restrict__ part, const int* __restrict__ lengths,
    float* __restrict__ ctx) {
  int h = blockIdx.x, b = blockIdx.y;
  int t = threadIdx.x;                           // 0..63 = d
  int n_keys = lengths[b];
  int nc = (n_keys + 127) >> 7;
  size_t base = ((size_t)(b * NHEADS + h)) * 8 * 66;
  float M = -INFINITY;
  for (int c2 = 0; c2 < nc; ++c2) M = fmaxf(M, part[base + c2 * 66]);
  float S = 0.0f, O = 0.0f;
  for (int c2 = 0; c2 < nc; ++c2) {
    float wv = __expf(part[base + c2 * 66] - M);
    S += wv * part[base + c2 * 66 + 1];
    O += wv * part[base + c2 * 66 + 2 + t];
  }
  ctx[b * 512 + h * 64 + t] = O / S;
}

// ---- kernel 7: MLP layer 1 (leaky_relu) ------------------------------------
__global__ __launch_bounds__(256) void mlp1_kernel(
    const float* __restrict__ ctx, const float* __restrict__ W1,
    const float* __restrict__ b1, float* __restrict__ hs) {
  int chunk = blockIdx.x, b = blockIdx.y;
  int t = threadIdx.x;
  __shared__ float xs[512];
  __shared__ float red[256];
  xs[t]       = ctx[b * 512 + t];
  xs[t + 256] = ctx[b * 512 + t + 256];
  __syncthreads();
  int col = chunk * 64 + (t & 63);
  int kp  = t >> 6;
  const float* wr = W1 + (size_t)col * 512 + kp * 128;
  const float* xp = xs + kp * 128;
  float a = 0.0f;
  for (int e = 0; e < 128; e += 4) {
    float4 wv = *(const float4*)(wr + e);
    a += wv.x * xp[e] + wv.y * xp[e + 1] + wv.z * xp[e + 2] + wv.w * xp[e + 3];
  }
  red[t] = a;
  __syncthreads();
  if (t < 64) {
    float v = red[t] + red[t + 64] + red[t + 128] + red[t + 192] + b1[chunk * 64 + t];
    hs[b * 512 + chunk * 64 + t] = (v > 0.0f) ? v : 0.01f * v;
  }
}

// ---- kernel 8: MLP layer 2 + mean + leaky ----------------------------------
__global__ __launch_bounds__(256) void mlp2_kernel(
    const float* __restrict__ hs, const float* __restrict__ W2,
    const float* __restrict__ b2, float* __restrict__ out) {
  int b = blockIdx.x, t = threadIdx.x;
  __shared__ float o8[8];
  int j = t >> 5, sub = t & 31;
  const float* hr  = hs + (size_t)b * 512;
  const float* w2r = W2 + (size_t)j * 512;
  float part = 0.0f;
  for (int e = sub * 16; e < sub * 16 + 16; e += 4) {
    float4 wv = *(const float4*)(w2r + e);
    float4 hv = *(const float4*)(hr + e);
    part += wv.x * hv.x + wv.y * hv.y + wv.z * hv.z + wv.w * hv.w;
  }
  #pragma unroll
  for (int o = 16; o > 0; o >>= 1) part += __shfl_xor(part, o, 64);
  if (sub == 0) o8[j] = fmaxf(part + b2[j], 0.0f);   // relu
  __syncthreads();
  if (t == 0) {
    float m = 0.0f;
    #pragma unroll
    for (int i = 0; i < 8; ++i) m += o8[i];
    m *= 0.125f;
    out[b] = (m > 0.0f) ? m : 0.01f * m;
  }
}

// ---- launcher --------------------------------------------------------------
extern "C" void kernel_launch(void* const* d_in, const int* in_sizes, int n_in,
                              void* d_out, int out_size, void* d_ws, size_t ws_size,
                              hipStream_t stream) {
  const int*   data    = (const int*)d_in[0];
  const int*   lengths = (const int*)d_in[1];
  const float* emb     = (const float*)d_in[2];
  const float* Wq      = (const float*)d_in[3];
  const float* bq      = (const float*)d_in[4];
  const float* Wk      = (const float*)d_in[5];
  const float* bk      = (const float*)d_in[6];
  const float* Wv      = (const float*)d_in[7];
  const float* bv      = (const float*)d_in[8];
  const float* W1      = (const float*)d_in[9];
  const float* b1      = (const float*)d_in[10];
  const float* W2      = (const float*)d_in[11];
  const float* b2      = (const float*)d_in[12];
  float* out = (float*)d_out;

  char* ws = (char*)d_ws;
  unsigned short* X    = (unsigned short*)(ws);                  // 33,554,432 B
  unsigned short* Ck   = (unsigned short*)(ws + 33554432);       // 33,554,432 B
  unsigned short* Cv   = (unsigned short*)(ws + 67108864);       // 33,554,432 B
  unsigned short* Bkv  = (unsigned short*)(ws + 100663296);      //  1,048,576 B
  float* bias_kv       = (float*)(ws + 101711872);               //      4,096 B
  float* qv            = (float*)(ws + 101715968);               //     65,536 B
  float* ctx           = (float*)(ws + 101781504);               //     65,536 B
  float* part          = (float*)(ws + 101847040);               //    540,672 B
  float* hs            = (float*)(ws + 102387712);               //     65,536 B

  prep_kernel<<<512, 256, 0, stream>>>(Wk, bk, Wv, bv, Bkv, bias_kv);
  build_x_kernel<<<8000, 256, 0, stream>>>(data, lengths, emb, X);
  dim3 g3(8, 8, BATCH);
  kv_gemm_kernel<<<g3, 256, 0, stream>>>(X, Bkv, bias_kv, lengths, Ck, Cv);
  dim3 g4(8, BATCH);
  q_proj_kernel<<<g4, 256, 0, stream>>>(X, lengths, Wq, bq, qv);
  dim3 g5(8, NHEADS, BATCH);
  attn_part_kernel<<<g5, 128, 0, stream>>>(qv, Ck, Cv, lengths, part);
  dim3 g6(NHEADS, BATCH);
  attn_combine_kernel<<<g6, 64, 0, stream>>>(part, lengths, ctx);
  dim3 g7(8, BATCH);
  mlp1_kernel<<<g7, 256, 0, stream>>>(ctx, W1, b1, hs);
  mlp2_kernel<<<BATCH, 256, 0, stream>>>(hs, W2, b2, out);
}

// Round 3
// 168.160 us; speedup vs baseline: 1.5101x; 1.0329x over previous
//
#include <hip/hip_runtime.h>
#include <math.h>

// ---- constants -------------------------------------------------------------
#define BATCH   32
#define LSEQ    1000
#define LPAD    1024
#define NHEADS  8
#define DHEAD   64

typedef __attribute__((ext_vector_type(8))) short s8v;   // 8 x bf16 (4 VGPRs)
typedef __attribute__((ext_vector_type(4))) float f4v;   // MFMA accumulator

__device__ __forceinline__ unsigned short f2bf(float f) {
  unsigned u = __builtin_bit_cast(unsigned, f);
  u += 0x7fffu + ((u >> 16) & 1u);           // RNE
  return (unsigned short)(u >> 16);
}
__device__ __forceinline__ float bf2f(unsigned short h) {
  return __builtin_bit_cast(float, ((unsigned)h) << 16);
}
__device__ __forceinline__ void g2lds16(const void* g, void* l) {
  __builtin_amdgcn_global_load_lds((const __attribute__((address_space(1))) void*)g,
                                   (__attribute__((address_space(3))) void*)l,
                                   16, 0, 0);
}

// ---- kernel A: fused [weights->bf16 B^T] U [X = emb+posenc] ----------------
__global__ __launch_bounds__(256) void prep_build_kernel(
    const float* __restrict__ Wk, const float* __restrict__ bk,
    const float* __restrict__ Wv, const float* __restrict__ bv,
    unsigned short* __restrict__ Bkv, float* __restrict__ bias_kv,
    const int* __restrict__ data, const int* __restrict__ lengths,
    const float* __restrict__ emb, unsigned short* __restrict__ X) {
  int t = threadIdx.x;
  if (blockIdx.x < 512) {                        // ---- prep part
    int idx = blockIdx.x * 256 + t;              // 131072 threads, 4 floats each
    int off = idx * 4;
    const float* s = (off < 262144) ? (Wk + off) : (Wv + off - 262144);
    float4 v = *(const float4*)s;
    unsigned r0 = (unsigned)f2bf(v.x) | ((unsigned)f2bf(v.y) << 16);
    unsigned r1 = (unsigned)f2bf(v.z) | ((unsigned)f2bf(v.w) << 16);
    uint2 pk; pk.x = r0; pk.y = r1;
    *(uint2*)(Bkv + off) = pk;
    if (idx < 1024) bias_kv[idx] = (idx < 512) ? bk[idx] : bv[idx - 512];
    return;
  }
  // ---- build_x part
  int row  = (blockIdx.x - 512) * 4 + (t >> 6);  // 0..31999
  int b    = row / 1000;
  int j    = row - b * 1000;
  int p    = lengths[b] - 1;
  if (j > p) return;
  int lane = t & 63;
  int e0   = lane * 8;
  int tok  = data[row];
  const float* ev = emb + (size_t)tok * 512 + e0;
  float4 a = *(const float4*)(ev);
  float4 c = *(const float4*)(ev + 4);
  float vals[8] = {a.x, a.y, a.z, a.w, c.x, c.y, c.z, c.w};
  #pragma unroll
  for (int i = 0; i < 8; i += 2) {
    int e = e0 + i;                              // even
    float dv  = __expf((float)e * (-9.210340371976184f / 512.0f)); // 10000^{-e/512}
    float arg = (float)j * dv;
    vals[i]     += __sinf(arg);
    vals[i + 1] += __cosf(arg);
  }
  unsigned w0 = (unsigned)f2bf(vals[0]) | ((unsigned)f2bf(vals[1]) << 16);
  unsigned w1 = (unsigned)f2bf(vals[2]) | ((unsigned)f2bf(vals[3]) << 16);
  unsigned w2 = (unsigned)f2bf(vals[4]) | ((unsigned)f2bf(vals[5]) << 16);
  unsigned w3 = (unsigned)f2bf(vals[6]) | ((unsigned)f2bf(vals[7]) << 16);
  uint4 pk; pk.x = w0; pk.y = w1; pk.z = w2; pk.w = w3;
  *(uint4*)(X + ((size_t)(b * LPAD + j)) * 512 + e0) = pk;
}

// ---- kernel B: q[b,h,:] = 0.125*(x[b,p] @ Wq^T + bq); bias_dot = <bk, q> ---
__global__ __launch_bounds__(256) void q_proj_kernel(
    const unsigned short* __restrict__ X, const int* __restrict__ lengths,
    const float* __restrict__ Wq, const float* __restrict__ bq,
    const float* __restrict__ bk,
    float* __restrict__ qv, float* __restrict__ bias_dot) {
  int h = blockIdx.x, b = blockIdx.y;            // h == 64-col chunk
  int p = lengths[b] - 1;
  int t = threadIdx.x;
  __shared__ float xs[512];
  __shared__ float red[256];
  const unsigned short* xr = X + ((size_t)(b * LPAD + p)) * 512;
  xs[t]       = bf2f(xr[t]);
  xs[t + 256] = bf2f(xr[t + 256]);
  __syncthreads();
  int col = h * 64 + (t & 63);
  int kp  = t >> 6;                              // 4-way K split
  const float* wr = Wq + (size_t)col * 512 + kp * 128;
  const float* xp = xs + kp * 128;
  float a = 0.0f;
  for (int e = 0; e < 128; e += 4) {
    float4 wv = *(const float4*)(wr + e);
    a += wv.x * xp[e] + wv.y * xp[e + 1] + wv.z * xp[e + 2] + wv.w * xp[e + 3];
  }
  red[t] = a;
  __syncthreads();
  if (t < 64) {                                  // wave 0 only
    float qval = (red[t] + red[t + 64] + red[t + 128] + red[t + 192]
                  + bq[h * 64 + t]) * 0.125f;    // pre-scale by 1/sqrt(64)
    qv[b * 512 + h * 64 + t] = qval;
    float bd = qval * bk[h * 64 + t];
    #pragma unroll
    for (int o = 32; o > 0; o >>= 1) bd += __shfl_xor(bd, o, 64);
    if (t == 0) bias_dot[b * NHEADS + h] = bd;
  }
}

// ---- kernel C: KV GEMM; K-half -> fp32 scores directly, V-half -> Cv -------
// 128x128 tile, BK=64, 4 waves of 64x64 (4x4 MFMA 16x16x32), XOR-swizzled LDS.
__global__ __launch_bounds__(256) void kv_gemm_kernel(
    const unsigned short* __restrict__ X, const unsigned short* __restrict__ Bkv,
    const float* __restrict__ bias_kv, const int* __restrict__ lengths,
    const float* __restrict__ qv, const float* __restrict__ bias_dot,
    float* __restrict__ scores, unsigned short* __restrict__ Cv) {
  int b    = blockIdx.z;
  int row0 = blockIdx.y * 128;
  int p    = lengths[b] - 1;
  if (row0 > p) return;
  int n0   = blockIdx.x * 128;                   // 0..896 over K(512)++V(512)

  __shared__ unsigned short lA[128 * 64];        // 16 KB
  __shared__ unsigned short lB[128 * 64];        // 16 KB

  int t = threadIdx.x;
  int w = t >> 6;
  int lane = t & 63;
  int wm = w & 1, wn = w >> 1;

  f4v acc[4][4];
  f4v z = {0.0f, 0.0f, 0.0f, 0.0f};
  #pragma unroll
  for (int i = 0; i < 4; ++i)
    #pragma unroll
    for (int jn = 0; jn < 4; ++jn) acc[i][jn] = z;

  const unsigned short* gA[4];
  const unsigned short* gB[4];
  #pragma unroll
  for (int i = 0; i < 4; ++i) {
    int chunk = (i * 4 + w) * 64 + lane;
    int r  = chunk >> 3;
    int cc = (chunk & 7) ^ (r & 7);
    gA[i] = X   + ((size_t)(b * LPAD + row0 + r)) * 512 + cc * 8;
    gB[i] = Bkv + ((size_t)(n0 + r)) * 512 + cc * 8;
  }

  int q  = lane >> 4;
  int ml = lane & 15;

  for (int kt = 0; kt < 8; ++kt) {               // K = 512, BK = 64
    #pragma unroll
    for (int i = 0; i < 4; ++i) {
      g2lds16(gA[i] + kt * 64, lA + (i * 4 + w) * 512);
      g2lds16(gB[i] + kt * 64, lB + (i * 4 + w) * 512);
    }
    __syncthreads();
    #pragma unroll
    for (int kk = 0; kk < 2; ++kk) {
      s8v af[4], bfr[4];
      #pragma unroll
      for (int mb = 0; mb < 4; ++mb) {
        int m  = wm * 64 + mb * 16 + ml;
        int ch = m * 8 + ((kk * 4 + q) ^ (m & 7));
        af[mb] = *(const s8v*)(&lA[ch * 8]);
      }
      #pragma unroll
      for (int nb = 0; nb < 4; ++nb) {
        int n  = wn * 64 + nb * 16 + ml;
        int ch = n * 8 + ((kk * 4 + q) ^ (n & 7));
        bfr[nb] = *(const s8v*)(&lB[ch * 8]);
      }
      #pragma unroll
      for (int mb = 0; mb < 4; ++mb)
        #pragma unroll
        for (int nb = 0; nb < 4; ++nb)
          acc[mb][nb] = __builtin_amdgcn_mfma_f32_16x16x32_bf16(
              af[mb], bfr[nb], acc[mb][nb], 0, 0, 0);
    }
    __syncthreads();
  }

  // epilogue. acc[mb][nb][r2]: row = wm*64+mb*16+q*4+r2, col = n0+wn*64+nb*16+ml
  if (blockIdx.x < 4) {
    // ---- K half: reduce against q-vector -> fp32 scores (Ck never stored)
    int h = blockIdx.x * 2 + wn;                 // this wave's head
    float qsv[4];
    #pragma unroll
    for (int nb = 0; nb < 4; ++nb)
      qsv[nb] = qv[b * 512 + h * 64 + nb * 16 + ml];
    float bd = bias_dot[b * NHEADS + h];
    size_t sbase = ((size_t)(b * NHEADS + h)) * LPAD + row0 + wm * 64;
    #pragma unroll
    for (int mb = 0; mb < 4; ++mb) {
      float pr[4];
      #pragma unroll
      for (int r2 = 0; r2 < 4; ++r2) {
        float sum = acc[mb][0][r2] * qsv[0] + acc[mb][1][r2] * qsv[1]
                  + acc[mb][2][r2] * qsv[2] + acc[mb][3][r2] * qsv[3];
        #pragma unroll
        for (int o = 1; o < 16; o <<= 1) sum += __shfl_xor(sum, o, 64);
        pr[r2] = sum;                            // valid on ml==0 lanes
      }
      if (ml == 0) {
        size_t sb = sbase + mb * 16 + q * 4;
        #pragma unroll
        for (int r2 = 0; r2 < 4; ++r2) scores[sb + r2] = pr[r2] + bd;
      }
    }
  } else {
    // ---- V half: head-major bf16 Cv[b][h][j][64]
    int nbase = n0 - 512;
    #pragma unroll
    for (int mb = 0; mb < 4; ++mb) {
      int row = row0 + wm * 64 + mb * 16 + q * 4;
      #pragma unroll
      for (int nb = 0; nb < 4; ++nb) {
        int col = nbase + wn * 64 + nb * 16 + ml;  // 0..511 within V
        int hh = col >> 6, d = col & 63;
        float bias = bias_kv[col + 512];
        size_t baseo = ((size_t)(b * NHEADS + hh) * LPAD + row) * 64 + d;
        #pragma unroll
        for (int r2 = 0; r2 < 4; ++r2)
          Cv[baseo + (size_t)r2 * 64] = f2bf(acc[mb][nb][r2] + bias);
      }
    }
  }
}

// ---- kernel D: attention partials per (chunk of 128 keys, h, b) ------------
__global__ __launch_bounds__(128) void attn_part_kernel(
    const float* __restrict__ scores, const unsigned short* __restrict__ Cv,
    const int* __restrict__ lengths, float* __restrict__ part) {
  int c = blockIdx.x, h = blockIdx.y, b = blockIdx.z;
  int n_keys = lengths[b];
  int j0 = c * 128;
  if (j0 >= n_keys) return;
  int t = threadIdx.x;
  __shared__ float redm[2];
  __shared__ float reds[2];
  __shared__ float probs[128];
  __shared__ float ored[128];
  int bh = b * NHEADS + h;
  int j = j0 + t;
  bool valid = j < n_keys;
  float s = scores[(size_t)bh * LPAD + j];
  float sc = valid ? s : -INFINITY;
  float wm = sc;
  #pragma unroll
  for (int o = 32; o > 0; o >>= 1) wm = fmaxf(wm, __shfl_xor(wm, o, 64));
  if ((t & 63) == 0) redm[t >> 6] = wm;
  __syncthreads();
  float m = fmaxf(redm[0], redm[1]);
  float pp = valid ? __expf(s - m) : 0.0f;
  probs[t] = pp;
  float ws_ = pp;
  #pragma unroll
  for (int o = 32; o > 0; o >>= 1) ws_ += __shfl_xor(ws_, o, 64);
  if ((t & 63) == 0) reds[t >> 6] = ws_;
  __syncthreads();
  // V pass: lane owns d, 2 waves stride j
  int lane = t & 63, w = t >> 6;
  const unsigned short* vr = Cv + ((size_t)bh * LPAD + j0) * 64 + lane;
  float a = 0.0f;
  for (int jl = w; jl < 128; jl += 2)
    a += probs[jl] * bf2f(vr[(size_t)jl * 64]);
  ored[t] = a;
  __syncthreads();
  size_t pi = ((size_t)bh * 8 + c) * 66;
  if (t < 64) part[pi + 2 + t] = ored[t] + ored[t + 64];
  if (t == 0) { part[pi] = m; part[pi + 1] = reds[0] + reds[1]; }
}

// ---- kernel E: combine partials -> ctx (in LDS) -> MLP layer 1 -------------
__global__ __launch_bounds__(256) void mlp1_kernel(
    const float* __restrict__ part, const int* __restrict__ lengths,
    const float* __restrict__ W1, const float* __restrict__ b1,
    float* __restrict__ hs) {
  int chunk = blockIdx.x, b = blockIdx.y;
  int t = threadIdx.x;
  __shared__ float xs[512];
  __shared__ float red[256];
  int n_keys = lengths[b];
  int nc = (n_keys + 127) >> 7;
  #pragma unroll
  for (int half = 0; half < 2; ++half) {
    int idx = half * 256 + t;                    // 0..511
    int h = idx >> 6, d = idx & 63;
    size_t base = ((size_t)(b * NHEADS + h)) * 8 * 66;
    float M = -INFINITY;
    for (int c2 = 0; c2 < nc; ++c2) M = fmaxf(M, part[base + c2 * 66]);
    float S = 0.0f, O = 0.0f;
    for (int c2 = 0; c2 < nc; ++c2) {
      float wv = __expf(part[base + c2 * 66] - M);
      S += wv * part[base + c2 * 66 + 1];
      O += wv * part[base + c2 * 66 + 2 + d];
    }
    xs[idx] = O / S;                             // ctx[b][h*64+d]
  }
  __syncthreads();
  int col = chunk * 64 + (t & 63);
  int kp  = t >> 6;
  const float* wr = W1 + (size_t)col * 512 + kp * 128;
  const float* xp = xs + kp * 128;
  float a = 0.0f;
  for (int e = 0; e < 128; e += 4) {
    float4 wv = *(const float4*)(wr + e);
    a += wv.x * xp[e] + wv.y * xp[e + 1] + wv.z * xp[e + 2] + wv.w * xp[e + 3];
  }
  red[t] = a;
  __syncthreads();
  if (t < 64) {
    float v = red[t] + red[t + 64] + red[t + 128] + red[t + 192] + b1[chunk * 64 + t];
    hs[b * 512 + chunk * 64 + t] = (v > 0.0f) ? v : 0.01f * v;
  }
}

// ---- kernel F: MLP layer 2 + mean + leaky ----------------------------------
__global__ __launch_bounds__(256) void mlp2_kernel(
    const float* __restrict__ hs, const float* __restrict__ W2,
    const float* __restrict__ b2, float* __restrict__ out) {
  int b = blockIdx.x, t = threadIdx.x;
  __shared__ float o8[8];
  int j = t >> 5, sub = t & 31;
  const float* hr  = hs + (size_t)b * 512;
  const float* w2r = W2 + (size_t)j * 512;
  float part = 0.0f;
  for (int e = sub * 16; e < sub * 16 + 16; e += 4) {
    float4 wv = *(const float4*)(w2r + e);
    float4 hv = *(const float4*)(hr + e);
    part += wv.x * hv.x + wv.y * hv.y + wv.z * hv.z + wv.w * hv.w;
  }
  #pragma unroll
  for (int o = 16; o > 0; o >>= 1) part += __shfl_xor(part, o, 64);
  if (sub == 0) o8[j] = fmaxf(part + b2[j], 0.0f);   // relu
  __syncthreads();
  if (t == 0) {
    float m = 0.0f;
    #pragma unroll
    for (int i = 0; i < 8; ++i) m += o8[i];
    m *= 0.125f;
    out[b] = (m > 0.0f) ? m : 0.01f * m;
  }
}

// ---- launcher --------------------------------------------------------------
extern "C" void kernel_launch(void* const* d_in, const int* in_sizes, int n_in,
                              void* d_out, int out_size, void* d_ws, size_t ws_size,
                              hipStream_t stream) {
  const int*   data    = (const int*)d_in[0];
  const int*   lengths = (const int*)d_in[1];
  const float* emb     = (const float*)d_in[2];
  const float* Wq      = (const float*)d_in[3];
  const float* bq      = (const float*)d_in[4];
  const float* Wk      = (const float*)d_in[5];
  const float* bk      = (const float*)d_in[6];
  const float* Wv      = (const float*)d_in[7];
  const float* bv      = (const float*)d_in[8];
  const float* W1      = (const float*)d_in[9];
  const float* b1      = (const float*)d_in[10];
  const float* W2      = (const float*)d_in[11];
  const float* b2      = (const float*)d_in[12];
  float* out = (float*)d_out;

  char* ws = (char*)d_ws;
  unsigned short* X    = (unsigned short*)(ws);                  // 33,554,432 B
  unsigned short* Cv   = (unsigned short*)(ws + 33554432);       // 33,554,432 B
  unsigned short* Bkv  = (unsigned short*)(ws + 67108864);       //  1,048,576 B
  float* bias_kv       = (float*)(ws + 68157440);                //      4,096 B
  float* qv            = (float*)(ws + 68161536);                //     65,536 B
  float* bias_dot      = (float*)(ws + 68227072);                //      1,024 B
  float* scores        = (float*)(ws + 68228096);                //  1,048,576 B
  float* part          = (float*)(ws + 69276672);                //    540,672 B
  float* hs            = (float*)(ws + 69817344);                //     65,536 B

  prep_build_kernel<<<8512, 256, 0, stream>>>(Wk, bk, Wv, bv, Bkv, bias_kv,
                                              data, lengths, emb, X);
  dim3 g2(NHEADS, BATCH);
  q_proj_kernel<<<g2, 256, 0, stream>>>(X, lengths, Wq, bq, bk, qv, bias_dot);
  dim3 g3(8, 8, BATCH);
  kv_gemm_kernel<<<g3, 256, 0, stream>>>(X, Bkv, bias_kv, lengths, qv, bias_dot,
                                         scores, Cv);
  dim3 g4(8, NHEADS, BATCH);
  attn_part_kernel<<<g4, 128, 0, stream>>>(scores, Cv, lengths, part);
  dim3 g5(8, BATCH);
  mlp1_kernel<<<g5, 256, 0, stream>>>(part, lengths, W1, b1, hs);
  mlp2_kernel<<<BATCH, 256, 0, stream>>>(hs, W2, b2, out);
}

// Round 4
// 155.819 us; speedup vs baseline: 1.6297x; 1.0792x over previous
//
#include <hip/hip_runtime.h>
#include <math.h>

// ---- constants -------------------------------------------------------------
#define BATCH   32
#define LSEQ    1000
#define LPAD    1024
#define NHEADS  8
#define DHEAD   64

__device__ __forceinline__ unsigned short f2bf(float f) {
  unsigned u = __builtin_bit_cast(unsigned, f);
  u += 0x7fffu + ((u >> 16) & 1u);           // RNE
  return (unsigned short)(u >> 16);
}
__device__ __forceinline__ float bf2f(unsigned short h) {
  return __builtin_bit_cast(float, ((unsigned)h) << 16);
}

// ---- K1: X[b][j][e] = bf16( emb[data[b,j]][e] + pe[j][e] ), j<=p_b ---------
__global__ __launch_bounds__(256) void build_x_kernel(
    const int* __restrict__ data, const int* __restrict__ lengths,
    const float* __restrict__ emb, unsigned short* __restrict__ X) {
  int t    = threadIdx.x;
  int row  = blockIdx.x * 4 + (t >> 6);          // 0..31999
  int b    = row / 1000;
  int j    = row - b * 1000;
  int p    = lengths[b] - 1;
  if (j > p) return;
  int lane = t & 63;
  int e0   = lane * 8;
  int tok  = data[row];
  const float* ev = emb + (size_t)tok * 512 + e0;
  float4 a = *(const float4*)(ev);
  float4 c = *(const float4*)(ev + 4);
  float vals[8] = {a.x, a.y, a.z, a.w, c.x, c.y, c.z, c.w};
  #pragma unroll
  for (int i = 0; i < 8; i += 2) {
    int e = e0 + i;                              // even
    float dv  = __expf((float)e * (-9.210340371976184f / 512.0f)); // 10000^{-e/512}
    float arg = (float)j * dv;
    vals[i]     += __sinf(arg);
    vals[i + 1] += __cosf(arg);
  }
  unsigned w0 = (unsigned)f2bf(vals[0]) | ((unsigned)f2bf(vals[1]) << 16);
  unsigned w1 = (unsigned)f2bf(vals[2]) | ((unsigned)f2bf(vals[3]) << 16);
  unsigned w2 = (unsigned)f2bf(vals[4]) | ((unsigned)f2bf(vals[5]) << 16);
  unsigned w3 = (unsigned)f2bf(vals[6]) | ((unsigned)f2bf(vals[7]) << 16);
  uint4 pk; pk.x = w0; pk.y = w1; pk.z = w2; pk.w = w3;
  *(uint4*)(X + ((size_t)(b * LPAD + j)) * 512 + e0) = pk;
}

// ---- K2: q̂[b,h,:] then wfold[b,h,e] = sum_d q̂[d]*Wk[h*64+d,e], bd = <bk,q̂> -
__global__ __launch_bounds__(256) void qfold_kernel(
    const unsigned short* __restrict__ X, const int* __restrict__ lengths,
    const float* __restrict__ Wq, const float* __restrict__ bq,
    const float* __restrict__ Wk, const float* __restrict__ bk,
    float* __restrict__ wfold, float* __restrict__ bias_dot) {
  int h = blockIdx.x, b = blockIdx.y;
  int p = lengths[b] - 1;
  int t = threadIdx.x;
  __shared__ float xs[512];
  __shared__ float red[256];
  __shared__ float qs[64];
  const unsigned short* xr = X + ((size_t)(b * LPAD + p)) * 512;
  xs[t]       = bf2f(xr[t]);
  xs[t + 256] = bf2f(xr[t + 256]);
  __syncthreads();
  int col = h * 64 + (t & 63);
  int kp  = t >> 6;                              // 4-way K split
  {
    const float* wr = Wq + (size_t)col * 512 + kp * 128;
    const float* xp = xs + kp * 128;
    float a = 0.0f;
    for (int e = 0; e < 128; e += 4) {
      float4 wv = *(const float4*)(wr + e);
      a += wv.x * xp[e] + wv.y * xp[e + 1] + wv.z * xp[e + 2] + wv.w * xp[e + 3];
    }
    red[t] = a;
  }
  __syncthreads();
  if (t < 64) {
    float qval = (red[t] + red[t + 64] + red[t + 128] + red[t + 192]
                  + bq[h * 64 + t]) * 0.125f;    // pre-scale by 1/sqrt(64)
    qs[t] = qval;
    float bd = qval * bk[h * 64 + t];
    #pragma unroll
    for (int o = 32; o > 0; o >>= 1) bd += __shfl_xor(bd, o, 64);
    if (t == 0) bias_dot[b * NHEADS + h] = bd;
  }
  __syncthreads();
  // fold: wfold[e] = sum_d qs[d] * Wk[(h*64+d)*512 + e], e = t and t+256
  float a0 = 0.0f, a1 = 0.0f;
  const float* wkb = Wk + (size_t)(h * 64) * 512;
  for (int d = 0; d < 64; ++d) {
    float qd = qs[d];
    a0 += qd * wkb[d * 512 + t];
    a1 += qd * wkb[d * 512 + t + 256];
  }
  size_t wb = ((size_t)(b * NHEADS + h)) * 512;
  wfold[wb + t]       = a0;
  wfold[wb + t + 256] = a1;
}

// ---- K3: scores[b,h,j] = X[b,j,:]·wfold[b,h,:] + bd  (wave-per-row) --------
__global__ __launch_bounds__(256) void score_kernel(
    const unsigned short* __restrict__ X, const float* __restrict__ wfold,
    const float* __restrict__ bias_dot, const int* __restrict__ lengths,
    float* __restrict__ scores) {
  int b = blockIdx.y;
  int n_keys = lengths[b];
  int row0 = blockIdx.x * 16;
  if (row0 >= n_keys) return;
  int t = threadIdx.x;
  int w = t >> 6, lane = t & 63;
  // per-lane wfold fragment: 8 heads x 8 elems (e = lane*8 + i)
  float wf[8][8];
  float bd[8];
  size_t wbase = ((size_t)b * NHEADS) * 512 + lane * 8;
  #pragma unroll
  for (int h = 0; h < 8; ++h) {
    float4 u0 = *(const float4*)(wfold + wbase + h * 512);
    float4 u1 = *(const float4*)(wfold + wbase + h * 512 + 4);
    wf[h][0] = u0.x; wf[h][1] = u0.y; wf[h][2] = u0.z; wf[h][3] = u0.w;
    wf[h][4] = u1.x; wf[h][5] = u1.y; wf[h][6] = u1.z; wf[h][7] = u1.w;
    bd[h] = bias_dot[b * NHEADS + h];
  }
  #pragma unroll
  for (int r = 0; r < 4; ++r) {
    int j = row0 + r * 4 + w;
    if (j >= n_keys) continue;
    const unsigned short* xr = X + ((size_t)(b * LPAD + j)) * 512 + lane * 8;
    uint4 u = *(const uint4*)xr;
    unsigned uu[4] = {u.x, u.y, u.z, u.w};
    float xf[8];
    #pragma unroll
    for (int wi = 0; wi < 4; ++wi) {
      xf[wi * 2]     = __builtin_bit_cast(float, uu[wi] << 16);
      xf[wi * 2 + 1] = __builtin_bit_cast(float, uu[wi] & 0xffff0000u);
    }
    #pragma unroll
    for (int h = 0; h < 8; ++h) {
      float s = xf[0] * wf[h][0] + xf[1] * wf[h][1] + xf[2] * wf[h][2]
              + xf[3] * wf[h][3] + xf[4] * wf[h][4] + xf[5] * wf[h][5]
              + xf[6] * wf[h][6] + xf[7] * wf[h][7];
      #pragma unroll
      for (int o = 1; o < 64; o <<= 1) s += __shfl_xor(s, o, 64);
      if (lane == 0)
        scores[((size_t)(b * NHEADS + h)) * LPAD + j] = s + bd[h];
    }
  }
}

// ---- K4: softmax over j per (b,h): probs = exp(s-max) (unnorm), sums=S -----
__global__ __launch_bounds__(256) void softmax_kernel(
    const float* __restrict__ scores, const int* __restrict__ lengths,
    float* __restrict__ probs, float* __restrict__ sums) {
  int h = blockIdx.x, b = blockIdx.y;
  int n = lengths[b];
  int t = threadIdx.x;
  __shared__ float red[4];
  size_t base = ((size_t)(b * NHEADS + h)) * LPAD;
  float lm = -INFINITY;
  for (int j = t; j < n; j += 256) lm = fmaxf(lm, scores[base + j]);
  #pragma unroll
  for (int o = 32; o > 0; o >>= 1) lm = fmaxf(lm, __shfl_xor(lm, o, 64));
  if ((t & 63) == 0) red[t >> 6] = lm;
  __syncthreads();
  float gmax = fmaxf(fmaxf(red[0], red[1]), fmaxf(red[2], red[3]));
  __syncthreads();
  float ls = 0.0f;
  for (int j = t; j < n; j += 256) {
    float e = __expf(scores[base + j] - gmax);
    probs[base + j] = e;
    ls += e;
  }
  #pragma unroll
  for (int o = 32; o > 0; o >>= 1) ls += __shfl_xor(ls, o, 64);
  if ((t & 63) == 0) red[t >> 6] = ls;
  __syncthreads();
  if (t == 0) sums[b * NHEADS + h] = red[0] + red[1] + red[2] + red[3];
}

// ---- K5: y_part[b,jc,w,h,e] = sum_{j in chunk, wave w} probs*X -------------
__global__ __launch_bounds__(256) void ypass_kernel(
    const unsigned short* __restrict__ X, const float* __restrict__ probs,
    const int* __restrict__ lengths, float* __restrict__ y_part) {
  int jc = blockIdx.x, b = blockIdx.y;
  int n_keys = lengths[b];
  int j0 = jc * 256;
  if (j0 >= n_keys) return;
  int cnt = min(256, n_keys - j0);
  int t = threadIdx.x;
  __shared__ float pl[8][256];
  #pragma unroll
  for (int h = 0; h < 8; ++h)
    pl[h][t] = (t < cnt) ? probs[((size_t)(b * NHEADS + h)) * LPAD + j0 + t] : 0.0f;
  __syncthreads();
  int w = t >> 6, lane = t & 63;
  float acc[8][8];
  #pragma unroll
  for (int h = 0; h < 8; ++h)
    #pragma unroll
    for (int i = 0; i < 8; ++i) acc[h][i] = 0.0f;
  for (int jj = w; jj < cnt; jj += 4) {
    const unsigned short* xr = X + ((size_t)(b * LPAD + j0 + jj)) * 512 + lane * 8;
    uint4 u = *(const uint4*)xr;
    unsigned uu[4] = {u.x, u.y, u.z, u.w};
    float xf[8];
    #pragma unroll
    for (int wi = 0; wi < 4; ++wi) {
      xf[wi * 2]     = __builtin_bit_cast(float, uu[wi] << 16);
      xf[wi * 2 + 1] = __builtin_bit_cast(float, uu[wi] & 0xffff0000u);
    }
    #pragma unroll
    for (int h = 0; h < 8; ++h) {
      float pj = pl[h][jj];
      #pragma unroll
      for (int i = 0; i < 8; ++i) acc[h][i] += pj * xf[i];
    }
  }
  // slot = ((b*4 + jc)*4 + w); layout [slot][h][512]
  size_t sb = (((size_t)(b * 4 + jc)) * 4 + w) * (8 * 512) + lane * 8;
  #pragma unroll
  for (int h = 0; h < 8; ++h)
    #pragma unroll
    for (int i = 0; i < 8; ++i) y_part[sb + h * 512 + i] = acc[h][i];
}

// ---- K6: ctx[b, h*64+d] = Wv[h*64+d,:]·(y/S) + bv --------------------------
__global__ __launch_bounds__(256) void ctx_kernel(
    const float* __restrict__ y_part, const float* __restrict__ sums,
    const int* __restrict__ lengths, const float* __restrict__ Wv,
    const float* __restrict__ bv, float* __restrict__ ctx) {
  int h = blockIdx.x, b = blockIdx.y;
  int t = threadIdx.x;
  __shared__ float ys[512];
  __shared__ float red[256];
  int n_keys = lengths[b];
  int nc = (n_keys + 255) >> 8;
  float inv = 1.0f / sums[b * NHEADS + h];
  float s0 = 0.0f, s1 = 0.0f;
  for (int jc = 0; jc < nc; ++jc) {
    #pragma unroll
    for (int w = 0; w < 4; ++w) {
      size_t sb = (((size_t)(b * 4 + jc)) * 4 + w) * (8 * 512) + h * 512;
      s0 += y_part[sb + t];
      s1 += y_part[sb + t + 256];
    }
  }
  ys[t]       = s0 * inv;
  ys[t + 256] = s1 * inv;
  __syncthreads();
  int col = h * 64 + (t & 63);
  int kp  = t >> 6;
  const float* wr = Wv + (size_t)col * 512 + kp * 128;
  const float* xp = ys + kp * 128;
  float a = 0.0f;
  for (int e = 0; e < 128; e += 4) {
    float4 wv = *(const float4*)(wr + e);
    a += wv.x * xp[e] + wv.y * xp[e + 1] + wv.z * xp[e + 2] + wv.w * xp[e + 3];
  }
  red[t] = a;
  __syncthreads();
  if (t < 64)
    ctx[b * 512 + h * 64 + t] =
        red[t] + red[t + 64] + red[t + 128] + red[t + 192] + bv[h * 64 + t];
}

// ---- K7: MLP layer 1 (leaky_relu) ------------------------------------------
__global__ __launch_bounds__(256) void mlp1_kernel(
    const float* __restrict__ ctx, const float* __restrict__ W1,
    const float* __restrict__ b1, float* __restrict__ hs) {
  int chunk = blockIdx.x, b = blockIdx.y;
  int t = threadIdx.x;
  __shared__ float xs[512];
  __shared__ float red[256];
  xs[t]       = ctx[b * 512 + t];
  xs[t + 256] = ctx[b * 512 + t + 256];
  __syncthreads();
  int col = chunk * 64 + (t & 63);
  int kp  = t >> 6;
  const float* wr = W1 + (size_t)col * 512 + kp * 128;
  const float* xp = xs + kp * 128;
  float a = 0.0f;
  for (int e = 0; e < 128; e += 4) {
    float4 wv = *(const float4*)(wr + e);
    a += wv.x * xp[e] + wv.y * xp[e + 1] + wv.z * xp[e + 2] + wv.w * xp[e + 3];
  }
  red[t] = a;
  __syncthreads();
  if (t < 64) {
    float v = red[t] + red[t + 64] + red[t + 128] + red[t + 192] + b1[chunk * 64 + t];
    hs[b * 512 + chunk * 64 + t] = (v > 0.0f) ? v : 0.01f * v;
  }
}

// ---- K8: MLP layer 2 + mean + leaky ----------------------------------------
__global__ __launch_bounds__(256) void mlp2_kernel(
    const float* __restrict__ hs, const float* __restrict__ W2,
    const float* __restrict__ b2, float* __restrict__ out) {
  int b = blockIdx.x, t = threadIdx.x;
  __shared__ float o8[8];
  int j = t >> 5, sub = t & 31;
  const float* hr  = hs + (size_t)b * 512;
  const float* w2r = W2 + (size_t)j * 512;
  float part = 0.0f;
  for (int e = sub * 16; e < sub * 16 + 16; e += 4) {
    float4 wv = *(const float4*)(w2r + e);
    float4 hv = *(const float4*)(hr + e);
    part += wv.x * hv.x + wv.y * hv.y + wv.z * hv.z + wv.w * hv.w;
  }
  #pragma unroll
  for (int o = 16; o > 0; o >>= 1) part += __shfl_xor(part, o, 64);
  if (sub == 0) o8[j] = fmaxf(part + b2[j], 0.0f);   // relu
  __syncthreads();
  if (t == 0) {
    float m = 0.0f;
    #pragma unroll
    for (int i = 0; i < 8; ++i) m += o8[i];
    m *= 0.125f;
    out[b] = (m > 0.0f) ? m : 0.01f * m;
  }
}

// ---- launcher --------------------------------------------------------------
extern "C" void kernel_launch(void* const* d_in, const int* in_sizes, int n_in,
                              void* d_out, int out_size, void* d_ws, size_t ws_size,
                              hipStream_t stream) {
  const int*   data    = (const int*)d_in[0];
  const int*   lengths = (const int*)d_in[1];
  const float* emb     = (const float*)d_in[2];
  const float* Wq      = (const float*)d_in[3];
  const float* bq      = (const float*)d_in[4];
  const float* Wk      = (const float*)d_in[5];
  const float* bk      = (const float*)d_in[6];
  const float* Wv      = (const float*)d_in[7];
  const float* bv      = (const float*)d_in[8];
  const float* W1      = (const float*)d_in[9];
  const float* b1      = (const float*)d_in[10];
  const float* W2      = (const float*)d_in[11];
  const float* b2      = (const float*)d_in[12];
  float* out = (float*)d_out;

  char* ws = (char*)d_ws;
  unsigned short* X = (unsigned short*)(ws);               // 33,554,432 B
  float* wfold      = (float*)(ws + 33554432);             //    524,288 B
  float* bias_dot   = (float*)(ws + 34078720);             //      1,024 B
  float* scores     = (float*)(ws + 34079744);             //  1,048,576 B
  float* probs      = (float*)(ws + 35128320);             //  1,048,576 B
  float* sums       = (float*)(ws + 36176896);             //      1,024 B
  float* y_part     = (float*)(ws + 36177920);             //  8,388,608 B
  float* ctx        = (float*)(ws + 44566528);             //     65,536 B
  float* hs         = (float*)(ws + 44632064);             //     65,536 B

  build_x_kernel<<<8000, 256, 0, stream>>>(data, lengths, emb, X);
  dim3 g2(NHEADS, BATCH);
  qfold_kernel<<<g2, 256, 0, stream>>>(X, lengths, Wq, bq, Wk, bk, wfold, bias_dot);
  dim3 g3(63, BATCH);
  score_kernel<<<g3, 256, 0, stream>>>(X, wfold, bias_dot, lengths, scores);
  dim3 g4(NHEADS, BATCH);
  softmax_kernel<<<g4, 256, 0, stream>>>(scores, lengths, probs, sums);
  dim3 g5(4, BATCH);
  ypass_kernel<<<g5, 256, 0, stream>>>(X, probs, lengths, y_part);
  dim3 g6(NHEADS, BATCH);
  ctx_kernel<<<g6, 256, 0, stream>>>(y_part, sums, lengths, Wv, bv, ctx);
  dim3 g7(8, BATCH);
  mlp1_kernel<<<g7, 256, 0, stream>>>(ctx, W1, b1, hs);
  mlp2_kernel<<<BATCH, 256, 0, stream>>>(hs, W2, b2, out);
}